// Round 1
// 444.562 us; speedup vs baseline: 1.0006x; 1.0006x over previous
//
#include <hip/hip_runtime.h>

// NoRA: out = P(x) / (1 + |Z(x)*x|), per-group coefficients adapted by LoRA.
// B=4, L=4096, D=4096, G=8, Dg=512, R=3. All tensors fp32.
// Memory-bound: 256 MB in + 256 MB out => roofline ~85 us @ 6.3 TB/s.
// Round 2: (a) hoist group coefficients out of the stream loop (g is
// loop-invariant: stride = 8192*256 = 2^21 ≡ 0 mod 1024, and g depends only
// on v mod 1024); (b) unroll x4 with all 4 loads issued before compute
// (4 KiB/wave in flight instead of 1 KiB); (c) non-temporal load/store —
// zero-reuse stream, don't retain in L2/L3.

#define NG 6   // numerator coeffs per group
#define DG 4   // denominator coeffs per group
#define GROUPS 8
#define RANK 3
#define SCALING 2.0f
#define EPS 1e-6f

typedef float f4 __attribute__((ext_vector_type(4)));

__device__ __forceinline__ float rat1(float xv,
                                      float a0, float a1, float a2,
                                      float a3, float a4, float a5,
                                      float b0, float b1, float b2, float b3)
{
    // P(x) = a0 + a1 x + ... + a5 x^5 (Horner)
    float p = fmaf(a5, xv, a4);
    p = fmaf(p, xv, a3);
    p = fmaf(p, xv, a2);
    p = fmaf(p, xv, a1);
    p = fmaf(p, xv, a0);
    // Z(x) = b0 + b1 x + b2 x^2 + b3 x^3 (Horner); Q = 1 + |Z*x|
    float z = fmaf(b3, xv, b2);
    z = fmaf(z, xv, b1);
    z = fmaf(z, xv, b0);
    const float q = 1.0f + fabsf(z * xv);
    return p * __builtin_amdgcn_rcpf(q);
}

__device__ __forceinline__ f4 rat4(f4 in,
                                   float a0, float a1, float a2,
                                   float a3, float a4, float a5,
                                   float b0, float b1, float b2, float b3)
{
    f4 o;
    o.x = rat1(in.x, a0, a1, a2, a3, a4, a5, b0, b1, b2, b3);
    o.y = rat1(in.y, a0, a1, a2, a3, a4, a5, b0, b1, b2, b3);
    o.z = rat1(in.z, a0, a1, a2, a3, a4, a5, b0, b1, b2, b3);
    o.w = rat1(in.w, a0, a1, a2, a3, a4, a5, b0, b1, b2, b3);
    return o;
}

__global__ __launch_bounds__(256) void nora_kernel(
    const float* __restrict__ x,          // [B*L*D]
    const float* __restrict__ base_num,   // [G,6]
    const float* __restrict__ base_den,   // [G,4]
    const float* __restrict__ lA_num,     // [R,6]
    const float* __restrict__ lB_num,     // [G,R]
    const float* __restrict__ lA_den,     // [R,4]
    const float* __restrict__ lB_den,     // [G,R]
    float* __restrict__ out,
    int n_vec)                            // total / 4
{
    __shared__ float s_num[GROUPS][NG];
    __shared__ float s_den[GROUPS][DG];

    const int tid = threadIdx.x;
    if (tid < GROUPS * NG) {                       // 48 threads: numerator coeffs
        const int g = tid / NG, k = tid % NG;
        float s = 0.f;
        #pragma unroll
        for (int r = 0; r < RANK; ++r)
            s += lB_num[g * RANK + r] * lA_num[r * NG + k];
        s_num[g][k] = base_num[tid] + SCALING * s;
    } else if (tid < GROUPS * NG + GROUPS * DG) {  // 32 threads: denominator coeffs
        const int t = tid - GROUPS * NG;
        const int g = t / DG, k = t % DG;
        float s = 0.f;
        #pragma unroll
        for (int r = 0; r < RANK; ++r)
            s += lB_den[g * RANK + r] * lA_den[r * DG + k];
        s_den[g][k] = base_den[t] + SCALING * s + EPS;
    }
    __syncthreads();

    const int stride = gridDim.x * blockDim.x;
    const int v0 = blockIdx.x * blockDim.x + tid;

    // element index = 4*v; channel = (4*v) % 4096; group = channel/512
    //   => g = (v >> 7) & 7, i.e. a function of (v mod 1024) only.
    // stride = 8192*256 = 2^21 is a multiple of 1024, so g is identical for
    // every iteration of this thread's grid-stride loop. Hoist all 10
    // coefficients into registers: the stream loop has ZERO LDS traffic.
    const int g = (v0 >> 7) & (GROUPS - 1);
    const float a0 = s_num[g][0], a1 = s_num[g][1], a2 = s_num[g][2];
    const float a3 = s_num[g][3], a4 = s_num[g][4], a5 = s_num[g][5];
    const float b0 = s_den[g][0], b1 = s_den[g][1];
    const float b2 = s_den[g][2], b3 = s_den[g][3];

    const f4* __restrict__ xv = (const f4*)x;
    f4* __restrict__ ov = (f4*)out;

    int v = v0;
    // Unroll x4: issue all 4 independent 16B loads before any compute so the
    // wave has 4 KiB in flight per trip; nt policy keeps the zero-reuse
    // stream from thrashing L2/L3.
    for (; v + 3 * stride < n_vec; v += 4 * stride) {
        const f4 i0 = __builtin_nontemporal_load(xv + v);
        const f4 i1 = __builtin_nontemporal_load(xv + v + stride);
        const f4 i2 = __builtin_nontemporal_load(xv + v + 2 * stride);
        const f4 i3 = __builtin_nontemporal_load(xv + v + 3 * stride);

        const f4 o0 = rat4(i0, a0, a1, a2, a3, a4, a5, b0, b1, b2, b3);
        const f4 o1 = rat4(i1, a0, a1, a2, a3, a4, a5, b0, b1, b2, b3);
        const f4 o2 = rat4(i2, a0, a1, a2, a3, a4, a5, b0, b1, b2, b3);
        const f4 o3 = rat4(i3, a0, a1, a2, a3, a4, a5, b0, b1, b2, b3);

        __builtin_nontemporal_store(o0, ov + v);
        __builtin_nontemporal_store(o1, ov + v + stride);
        __builtin_nontemporal_store(o2, ov + v + 2 * stride);
        __builtin_nontemporal_store(o3, ov + v + 3 * stride);
    }
    // Tail (never taken at the shipped shape: n_vec = 8 * stride exactly).
    for (; v < n_vec; v += stride) {
        const f4 i = __builtin_nontemporal_load(xv + v);
        __builtin_nontemporal_store(
            rat4(i, a0, a1, a2, a3, a4, a5, b0, b1, b2, b3), ov + v);
    }
}

extern "C" void kernel_launch(void* const* d_in, const int* in_sizes, int n_in,
                              void* d_out, int out_size, void* d_ws, size_t ws_size,
                              hipStream_t stream) {
    const float* x   = (const float*)d_in[0];
    const float* bn  = (const float*)d_in[1];
    const float* bd  = (const float*)d_in[2];
    const float* lAn = (const float*)d_in[3];
    const float* lBn = (const float*)d_in[4];
    const float* lAd = (const float*)d_in[5];
    const float* lBd = (const float*)d_in[6];
    float* out = (float*)d_out;

    const int n = in_sizes[0];          // 4*4096*4096 = 67108864, divisible by 4
    const int n_vec = n / 4;            // 16777216 float4 vectors

    const int block = 256;
    const int grid  = 8192;             // stride = 2^21 (multiple of 1024: keeps
                                        // per-thread group loop-invariant)
    hipLaunchKernelGGL(nora_kernel, dim3(grid), dim3(block), 0, stream,
                       x, bn, bd, lAn, lBn, lAd, lBd, out, n_vec);
}

// Round 2
// 434.497 us; speedup vs baseline: 1.0238x; 1.0232x over previous
//
#include <hip/hip_runtime.h>

// NoRA: out = P(x) / (1 + |Z(x)*x|), per-group coefficients adapted by LoRA.
// B=4, L=4096, D=4096, G=8, Dg=512, R=3. All tensors fp32.
// Memory-bound: 256 MB in + 256 MB out => kernel roofline ~85 us @ 6.3 TB/s
// (copy ceiling, m13). Timed score also contains 2x ~163 us harness poison
// fills => score floor ~412 us.
//
// Round 3: access-geometry change. Previous rounds used 32 MiB grid-stride
// with unroll x4 => every wave drove 8 DRAM streams 32 MiB apart (~16K
// concurrent streams chip-wide -> row thrash). Now: 1024-thread blocks,
// each block owns ONE contiguous 128 KiB tile and sweeps it linearly.
// chunk = 1024 vectors = exactly one group period (group = (v>>7)&7), so
// with base % 8192 == 0 each thread's group is (tid>>7)&7 for EVERY chunk:
// coefficients hoist to 10 registers, wave-uniform, zero LDS in the loop.

#define NG 6   // numerator coeffs per group
#define DG 4   // denominator coeffs per group
#define GROUPS 8
#define RANK 3
#define SCALING 2.0f
#define EPS 1e-6f

typedef float f4 __attribute__((ext_vector_type(4)));

__device__ __forceinline__ float rat1(float xv,
                                      float a0, float a1, float a2,
                                      float a3, float a4, float a5,
                                      float b0, float b1, float b2, float b3)
{
    // P(x) = a0 + a1 x + ... + a5 x^5 (Horner)
    float p = fmaf(a5, xv, a4);
    p = fmaf(p, xv, a3);
    p = fmaf(p, xv, a2);
    p = fmaf(p, xv, a1);
    p = fmaf(p, xv, a0);
    // Z(x) = b0 + b1 x + b2 x^2 + b3 x^3 (Horner); Q = 1 + |Z*x|
    float z = fmaf(b3, xv, b2);
    z = fmaf(z, xv, b1);
    z = fmaf(z, xv, b0);
    const float q = 1.0f + fabsf(z * xv);
    return p * __builtin_amdgcn_rcpf(q);
}

__device__ __forceinline__ f4 rat4(f4 in,
                                   float a0, float a1, float a2,
                                   float a3, float a4, float a5,
                                   float b0, float b1, float b2, float b3)
{
    f4 o;
    o.x = rat1(in.x, a0, a1, a2, a3, a4, a5, b0, b1, b2, b3);
    o.y = rat1(in.y, a0, a1, a2, a3, a4, a5, b0, b1, b2, b3);
    o.z = rat1(in.z, a0, a1, a2, a3, a4, a5, b0, b1, b2, b3);
    o.w = rat1(in.w, a0, a1, a2, a3, a4, a5, b0, b1, b2, b3);
    return o;
}

#define VEC_PER_BLOCK 8192   // 1024 threads x 8 float4 = 128 KiB tile
#define CHUNK 1024           // vectors per chunk = one group period

__global__ __launch_bounds__(1024) void nora_kernel(
    const float* __restrict__ x,          // [B*L*D]
    const float* __restrict__ base_num,   // [G,6]
    const float* __restrict__ base_den,   // [G,4]
    const float* __restrict__ lA_num,     // [R,6]
    const float* __restrict__ lB_num,     // [G,R]
    const float* __restrict__ lA_den,     // [R,4]
    const float* __restrict__ lB_den,     // [G,R]
    float* __restrict__ out,
    int n_vec)                            // total / 4
{
    __shared__ float s_num[GROUPS][NG];
    __shared__ float s_den[GROUPS][DG];

    const int tid = threadIdx.x;
    if (tid < GROUPS * NG) {                       // 48 threads: numerator coeffs
        const int g = tid / NG, k = tid % NG;
        float s = 0.f;
        #pragma unroll
        for (int r = 0; r < RANK; ++r)
            s += lB_num[g * RANK + r] * lA_num[r * NG + k];
        s_num[g][k] = base_num[tid] + SCALING * s;
    } else if (tid < GROUPS * NG + GROUPS * DG) {  // 32 threads: denominator coeffs
        const int t = tid - GROUPS * NG;
        const int g = t / DG, k = t % DG;
        float s = 0.f;
        #pragma unroll
        for (int r = 0; r < RANK; ++r)
            s += lB_den[g * RANK + r] * lA_den[r * DG + k];
        s_den[g][k] = base_den[t] + SCALING * s + EPS;
    }
    __syncthreads();

    // v = base + j*1024 + tid with base % 8192 == 0
    //   => group = (v>>7)&7 = (tid>>7)&7, identical for every chunk j.
    // Wave-uniform (tid>>7 constant within a 64-lane wave).
    const int g = (tid >> 7) & (GROUPS - 1);
    const float a0 = s_num[g][0], a1 = s_num[g][1], a2 = s_num[g][2];
    const float a3 = s_num[g][3], a4 = s_num[g][4], a5 = s_num[g][5];
    const float b0 = s_den[g][0], b1 = s_den[g][1];
    const float b2 = s_den[g][2], b3 = s_den[g][3];

    const f4* __restrict__ xv4 = (const f4*)x;
    f4* __restrict__ ov4 = (f4*)out;

    const int base = blockIdx.x * VEC_PER_BLOCK;

    if (base + VEC_PER_BLOCK <= n_vec) {
        // Full tile: 2 trips x 4 chunks; each trip reads/writes 16 KiB
        // contiguous at block level; 4 KiB in flight per wave per trip.
        #pragma unroll
        for (int jg = 0; jg < 2; ++jg) {
            const int v0 = base + jg * (4 * CHUNK) + tid;
            const f4 i0 = __builtin_nontemporal_load(xv4 + v0);
            const f4 i1 = __builtin_nontemporal_load(xv4 + v0 + CHUNK);
            const f4 i2 = __builtin_nontemporal_load(xv4 + v0 + 2 * CHUNK);
            const f4 i3 = __builtin_nontemporal_load(xv4 + v0 + 3 * CHUNK);

            const f4 o0 = rat4(i0, a0, a1, a2, a3, a4, a5, b0, b1, b2, b3);
            const f4 o1 = rat4(i1, a0, a1, a2, a3, a4, a5, b0, b1, b2, b3);
            const f4 o2 = rat4(i2, a0, a1, a2, a3, a4, a5, b0, b1, b2, b3);
            const f4 o3 = rat4(i3, a0, a1, a2, a3, a4, a5, b0, b1, b2, b3);

            __builtin_nontemporal_store(o0, ov4 + v0);
            __builtin_nontemporal_store(o1, ov4 + v0 + CHUNK);
            __builtin_nontemporal_store(o2, ov4 + v0 + 2 * CHUNK);
            __builtin_nontemporal_store(o3, ov4 + v0 + 3 * CHUNK);
        }
    } else {
        // Partial last tile (not taken at shipped shape: n_vec = 2048*8192).
        for (int j = 0; j < 8; ++j) {
            const int v = base + j * CHUNK + tid;
            if (v < n_vec) {
                const f4 i = __builtin_nontemporal_load(xv4 + v);
                __builtin_nontemporal_store(
                    rat4(i, a0, a1, a2, a3, a4, a5, b0, b1, b2, b3), ov4 + v);
            }
        }
    }
}

extern "C" void kernel_launch(void* const* d_in, const int* in_sizes, int n_in,
                              void* d_out, int out_size, void* d_ws, size_t ws_size,
                              hipStream_t stream) {
    const float* x   = (const float*)d_in[0];
    const float* bn  = (const float*)d_in[1];
    const float* bd  = (const float*)d_in[2];
    const float* lAn = (const float*)d_in[3];
    const float* lBn = (const float*)d_in[4];
    const float* lAd = (const float*)d_in[5];
    const float* lBd = (const float*)d_in[6];
    float* out = (float*)d_out;

    const int n = in_sizes[0];          // 4*4096*4096 = 67108864, divisible by 4
    const int n_vec = n / 4;            // 16777216 float4 vectors

    const int block = 1024;
    const int grid  = (n_vec + VEC_PER_BLOCK - 1) / VEC_PER_BLOCK;  // 2048
    hipLaunchKernelGGL(nora_kernel, dim3(grid), dim3(block), 0, stream,
                       x, bn, bd, lAn, lBn, lAd, lBd, out, n_vec);
}